// Round 4
// baseline (159.294 us; speedup 1.0000x reference)
//
#include <hip/hip_runtime.h>
#include <math.h>

// Problem constants (from reference): w=0.05, b=5.803, single species.
#define NBINS_MAX 512
#define NMAX      1024            // atom capacity for LDS staging (N=1024)
constexpr float KW      = 0.05f;
constexpr float INV_KW  = 20.0f;           // 1/w
constexpr float CUT     = 8.0f * KW;       // truncate Gaussian at 8 sigma (omitted mass ~1e-12 in G)
constexpr float GNORM   = 0.3989422804014327f * INV_KW; // 1/(w*sqrt(2pi))
constexpr float COEFF   = 0.33674809f;     // b*b*0.01 = 5.803^2*0.01
constexpr float FOUR_PI = 12.566370614359172f;

// ---------------------------------------------------------------------------
// Kernel 1: pairwise min-image distances -> truncated-Gaussian KDE histogram.
// 1024 threads/block -> 2 blocks/CU -> 32 waves/CU (full occupancy).
// Positions staged in LDS (SoA) so the pair loop has no global-latency term.
// Block b handles rows (b, N-1-b): exactly N-1 pairs, one pair per thread.
// Output: per-block partial histogram, plain coalesced stores (no atomics).
// ---------------------------------------------------------------------------
__global__ void __launch_bounds__(1024)
pair_hist_kernel(const float* __restrict__ pos,
                 const float* __restrict__ cell,
                 const float* __restrict__ rbins,
                 float* __restrict__ partial,   // [gridDim.x][nbins]
                 int N, int nbins)
{
    __shared__ float sh_px[NMAX], sh_py[NMAX], sh_pz[NMAX];
    __shared__ float sh_hist[NBINS_MAX];
    const int t = threadIdx.x;

    for (int k = t; k < nbins; k += blockDim.x) sh_hist[k] = 0.0f;
    for (int i = t; i < N; i += blockDim.x) {
        sh_px[i] = pos[3*i + 0];
        sh_py[i] = pos[3*i + 1];
        sh_pz[i] = pos[3*i + 2];
    }

    // cell (wave-uniform scalar loads) and its inverse
    float cm[9];
#pragma unroll
    for (int k = 0; k < 9; ++k) cm[k] = cell[k];
    const float a00 = cm[0], a01 = cm[1], a02 = cm[2];
    const float a10 = cm[3], a11 = cm[4], a12 = cm[5];
    const float a20 = cm[6], a21 = cm[7], a22 = cm[8];
    const float det = a00*(a11*a22 - a12*a21)
                    - a01*(a10*a22 - a12*a20)
                    + a02*(a10*a21 - a11*a20);
    const float id = 1.0f / det;
    float im[9];
    im[0] = (a11*a22 - a12*a21)*id;
    im[1] = (a02*a21 - a01*a22)*id;
    im[2] = (a01*a12 - a02*a11)*id;
    im[3] = (a12*a20 - a10*a22)*id;
    im[4] = (a00*a22 - a02*a20)*id;
    im[5] = (a02*a10 - a00*a12)*id;
    im[6] = (a10*a21 - a11*a20)*id;
    im[7] = (a01*a20 - a00*a21)*id;
    im[8] = (a00*a11 - a01*a10)*id;

    const float r0     = rbins[0];
    const float rend   = rbins[nbins - 1];
    const float dr     = (rend - r0) / (float)(nbins - 1);
    const float inv_dr = 1.0f / dr;
    const float minb   = r0   - 3.0f * KW;   // window mask excludes whole pairs
    const float maxb   = rend + 3.0f * KW;
    const float ustep  = dr * INV_KW;

    __syncthreads();

    // Row pairing: A = b, B = N-1-b. cntA = N-1-A pairs (j>A), cntB = A pairs.
    const int A    = blockIdx.x;
    const int B    = N - 1 - A;
    const int cntA = N - 1 - A;
    const int cntB = (B != A) ? A : 0;   // guard for odd N center row
    const int tot  = cntA + cntB;

    for (int p = t; p < tot; p += blockDim.x) {   // one iteration when N-1 <= 1024
        int i, j;
        if (p < cntA) { i = A; j = A + 1 + p; }
        else          { i = B; j = B + 1 + (p - cntA); }

        const float dx = sh_px[j] - sh_px[i];
        const float dy = sh_py[j] - sh_py[i];
        const float dz = sh_pz[j] - sh_pz[i];
        // frac = diff @ cell_inv
        float fx = dx*im[0] + dy*im[3] + dz*im[6];
        float fy = dx*im[1] + dy*im[4] + dz*im[7];
        float fz = dx*im[2] + dy*im[5] + dz*im[8];
        // minimum image (rintf = round-half-even = jnp.round)
        fx -= rintf(fx); fy -= rintf(fy); fz -= rintf(fz);
        // mip = frac @ cell
        const float mx = fx*cm[0] + fy*cm[3] + fz*cm[6];
        const float my = fx*cm[1] + fy*cm[4] + fz*cm[7];
        const float mz = fx*cm[2] + fy*cm[5] + fz*cm[8];
        const float d  = sqrtf(mx*mx + my*my + mz*mz + 1e-10f);

        if (!(d > minb && d < maxb)) continue;

        int lo = (int)ceilf ((d - CUT - r0) * inv_dr);
        int hi = (int)floorf((d + CUT - r0) * inv_dr);
        if (lo < 0) lo = 0;
        if (hi > nbins - 1) hi = nbins - 1;

        // u_k = (r_k - d)/w advanced incrementally; body: mul,mul,exp,mul,ds_add.
        float u = (r0 + (float)lo * dr - d) * INV_KW;
        for (int k = lo; k <= hi; ++k) {
            unsafeAtomicAdd(&sh_hist[k], __expf(-0.5f * u * u) * GNORM);
            u += ustep;
        }
    }

    __syncthreads();
    float* myrow = partial + (size_t)blockIdx.x * nbins;
    for (int k = t; k < nbins; k += blockDim.x) myrow[k] = sh_hist[k];
}

// ---------------------------------------------------------------------------
// Kernel 2 (single block, 1024 threads): reduce partials -> gsum, compute
// G(r) (written by threads 0..nbins-1), then one wave per Q computes the
// trapezoid integral for S(Q), F(Q) from LDS. 2 dispatches total per launch.
// ---------------------------------------------------------------------------
__global__ void __launch_bounds__(1024)
reduce_finalize_kernel(const float* __restrict__ partial,
                       const float* __restrict__ cell,
                       const float* __restrict__ rbins,
                       const float* __restrict__ qbins,
                       float* __restrict__ out,
                       int N, int nbins, int npart)
{
    __shared__ float sh_G[NBINS_MAX];
    __shared__ float sh_r[NBINS_MAX];
    const int t = threadIdx.x;

    const float a00 = cell[0], a01 = cell[1], a02 = cell[2];
    const float a10 = cell[3], a11 = cell[4], a12 = cell[5];
    const float a20 = cell[6], a21 = cell[7], a22 = cell[8];
    const float det = a00*(a11*a22 - a12*a21)
                    - a01*(a10*a22 - a12*a20)
                    + a02*(a10*a21 - a11*a20);
    const float vol     = fabsf(det);
    const float n_pairs = 0.5f * (float)N * (float)(N - 1);
    const float rho     = (float)N / vol;
    const float pref    = vol / n_pairs;

    if (t < nbins) {
        // column-sum over npart rows; 4 accumulators for MLP/ILP
        float s0 = 0.0f, s1 = 0.0f, s2 = 0.0f, s3 = 0.0f;
        int p = 0;
        for (; p + 4 <= npart; p += 4) {
            s0 += partial[(size_t)(p+0)*nbins + t];
            s1 += partial[(size_t)(p+1)*nbins + t];
            s2 += partial[(size_t)(p+2)*nbins + t];
            s3 += partial[(size_t)(p+3)*nbins + t];
        }
        for (; p < npart; ++p) s0 += partial[(size_t)p*nbins + t];
        const float summed = (s0 + s1) + (s2 + s3);

        const float r = rbins[t];
        const float g = pref * summed / (FOUR_PI * r * r);
        const float G = COEFF * (g - 1.0f);
        out[t]  = G;      // G(r)
        sh_G[t] = G;
        sh_r[t] = r;
    }
    __syncthreads();

    const int wid  = t >> 6;
    const int lane = t & 63;
    const int nw   = blockDim.x >> 6;
    for (int qi = wid; qi < nbins; qi += nw) {
        const float q    = qbins[qi];
        const float qinv = 1.0f / (q + 1e-10f);
        float acc = 0.0f;
        for (int k = lane; k < nbins; k += 64) {
            const float r    = sh_r[k];
            const float w_lo = (k > 0)         ? (r - sh_r[k - 1]) : 0.0f;
            const float w_hi = (k < nbins - 1) ? (sh_r[k + 1] - r) : 0.0f;
            acc += 0.5f * (w_lo + w_hi) * r * sh_G[k] * __sinf(q * r) * qinv;
        }
#pragma unroll
        for (int off = 32; off > 0; off >>= 1)
            acc += __shfl_down(acc, off, 64);
        if (lane == 0) {
            const float S = 1.0f + FOUR_PI * rho * acc;
            out[nbins + qi]   = S;               // S(Q)
            out[2*nbins + qi] = q * (S - 1.0f);  // F(Q)
        }
    }
}

// ---------------------------------------------------------------------------
extern "C" void kernel_launch(void* const* d_in, const int* in_sizes, int n_in,
                              void* d_out, int out_size, void* d_ws, size_t ws_size,
                              hipStream_t stream)
{
    const float* pos   = (const float*)d_in[0];  // (N,3) f32
    const float* cell  = (const float*)d_in[1];  // (3,3) f32
    const float* rbins = (const float*)d_in[2];  // (nbins,) f32
    const float* qbins = (const float*)d_in[3];  // (nbins,) f32
    float* out = (float*)d_out;                  // (3, nbins) f32

    const int N     = in_sizes[0] / 3;
    const int nbins = in_sizes[2];
    const int npart = (N + 1) / 2;               // pair-kernel block count

    float* partial = (float*)d_ws;               // [npart][nbins]

    hipLaunchKernelGGL(pair_hist_kernel, dim3(npart), dim3(1024), 0, stream,
                       pos, cell, rbins, partial, N, nbins);
    hipLaunchKernelGGL(reduce_finalize_kernel, dim3(1), dim3(1024), 0, stream,
                       partial, cell, rbins, qbins, out, N, nbins, npart);
}

// Round 5
// 129.880 us; speedup vs baseline: 1.2265x; 1.2265x over previous
//
#include <hip/hip_runtime.h>
#include <math.h>

// Problem constants (from reference): w=0.05, b=5.803, single species.
#define NBINS_MAX 512
#define NMAX      1024            // atom capacity for LDS staging (N=1024)
#define NPART_MAX 128             // pair-kernel block count (keeps partial L2-small)
constexpr float KW      = 0.05f;
constexpr float INV_KW  = 20.0f;           // 1/w
constexpr float CUT     = 8.0f * KW;       // truncate Gaussian at 8 sigma (omitted mass ~1e-12 in G)
constexpr float GNORM   = 0.3989422804014327f * INV_KW; // 1/(w*sqrt(2pi))
constexpr float COEFF   = 0.33674809f;     // b*b*0.01 = 5.803^2*0.01
constexpr float FOUR_PI = 12.566370614359172f;

// ---------------------------------------------------------------------------
// Kernel 1: pairwise min-image distances -> truncated-Gaussian KDE histogram.
// 128 blocks x 1024 thr; block b grid-strides over row-pairs (A=rp, B=N-1-rp:
// exactly N-1 pairs each -> perfect balance, no division, no discarded lanes).
// Positions staged in LDS (SoA); inner KDE loop is pure VALU + native
// ds_add_f32 (unsafeAtomicAdd). Flush: plain coalesced stores into
// partial[128][nbins] (no global atomics -- R1 showed the 205k device-scope
// fp atomics were a serialized ~40us chain).
// ---------------------------------------------------------------------------
__global__ void __launch_bounds__(1024)
pair_hist_kernel(const float* __restrict__ pos,
                 const float* __restrict__ cell,
                 const float* __restrict__ rbins,
                 float* __restrict__ partial,   // [gridDim.x][nbins]
                 int N, int nbins)
{
    __shared__ float sh_px[NMAX], sh_py[NMAX], sh_pz[NMAX];
    __shared__ float sh_hist[NBINS_MAX];
    const int t = threadIdx.x;

    for (int k = t; k < nbins; k += blockDim.x) sh_hist[k] = 0.0f;
    for (int i = t; i < N; i += blockDim.x) {
        sh_px[i] = pos[3*i + 0];
        sh_py[i] = pos[3*i + 1];
        sh_pz[i] = pos[3*i + 2];
    }

    // cell (wave-uniform scalar loads) and its inverse
    float cm[9];
#pragma unroll
    for (int k = 0; k < 9; ++k) cm[k] = cell[k];
    const float a00 = cm[0], a01 = cm[1], a02 = cm[2];
    const float a10 = cm[3], a11 = cm[4], a12 = cm[5];
    const float a20 = cm[6], a21 = cm[7], a22 = cm[8];
    const float det = a00*(a11*a22 - a12*a21)
                    - a01*(a10*a22 - a12*a20)
                    + a02*(a10*a21 - a11*a20);
    const float id = 1.0f / det;
    float im[9];
    im[0] = (a11*a22 - a12*a21)*id;
    im[1] = (a02*a21 - a01*a22)*id;
    im[2] = (a01*a12 - a02*a11)*id;
    im[3] = (a12*a20 - a10*a22)*id;
    im[4] = (a00*a22 - a02*a20)*id;
    im[5] = (a02*a10 - a00*a12)*id;
    im[6] = (a10*a21 - a11*a20)*id;
    im[7] = (a01*a20 - a00*a21)*id;
    im[8] = (a00*a11 - a01*a10)*id;

    const float r0     = rbins[0];
    const float rend   = rbins[nbins - 1];
    const float dr     = (rend - r0) / (float)(nbins - 1);
    const float inv_dr = 1.0f / dr;
    const float minb   = r0   - 3.0f * KW;   // window mask excludes whole pairs
    const float maxb   = rend + 3.0f * KW;
    const float ustep  = dr * INV_KW;

    __syncthreads();

    const int nrp = (N + 1) / 2;   // row-pairs; each = N-1 pairs
    for (int rp = blockIdx.x; rp < nrp; rp += gridDim.x) {
        const int A    = rp;
        const int B    = N - 1 - rp;
        const int cntA = N - 1 - A;          // pairs (A, j>A)
        const int cntB = (B != A) ? A : 0;   // pairs (B, j>B); guard odd-N center
        const int tot  = cntA + cntB;

        for (int p = t; p < tot; p += blockDim.x) {
            int i, j;
            if (p < cntA) { i = A; j = A + 1 + p; }
            else          { i = B; j = B + 1 + (p - cntA); }

            const float dx = sh_px[j] - sh_px[i];
            const float dy = sh_py[j] - sh_py[i];
            const float dz = sh_pz[j] - sh_pz[i];
            // frac = diff @ cell_inv
            float fx = dx*im[0] + dy*im[3] + dz*im[6];
            float fy = dx*im[1] + dy*im[4] + dz*im[7];
            float fz = dx*im[2] + dy*im[5] + dz*im[8];
            // minimum image (rintf = round-half-even = jnp.round)
            fx -= rintf(fx); fy -= rintf(fy); fz -= rintf(fz);
            // mip = frac @ cell
            const float mx = fx*cm[0] + fy*cm[3] + fz*cm[6];
            const float my = fx*cm[1] + fy*cm[4] + fz*cm[7];
            const float mz = fx*cm[2] + fy*cm[5] + fz*cm[8];
            const float d  = sqrtf(mx*mx + my*my + mz*mz + 1e-10f);

            if (!(d > minb && d < maxb)) continue;

            int lo = (int)ceilf ((d - CUT - r0) * inv_dr);
            int hi = (int)floorf((d + CUT - r0) * inv_dr);
            if (lo < 0) lo = 0;
            if (hi > nbins - 1) hi = nbins - 1;

            // u_k = (r_k - d)/w advanced incrementally; body: mul,exp,mul,ds_add.
            float u = (r0 + (float)lo * dr - d) * INV_KW;
            for (int k = lo; k <= hi; ++k) {
                unsafeAtomicAdd(&sh_hist[k], __expf(-0.5f * u * u) * GNORM);
                u += ustep;
            }
        }
    }

    __syncthreads();
    float* myrow = partial + (size_t)blockIdx.x * nbins;
    for (int k = t; k < nbins; k += blockDim.x) myrow[k] = sh_hist[k];
}

// ---------------------------------------------------------------------------
// Kernel 2: one block per Q (400 blocks x 256 thr). Each block re-reduces the
// whole partial[npart][nbins] (L2-resident, ~205 KB) into G(r) in LDS, then
// does its Q's trapezoid integral. Block 0 also writes G(r). Fully parallel --
// R4's single-block version of this measured 77us at 0.17% occupancy.
// ---------------------------------------------------------------------------
__global__ void __launch_bounds__(256)
finalize_kernel(const float* __restrict__ partial,
                const float* __restrict__ cell,
                const float* __restrict__ rbins,
                const float* __restrict__ qbins,
                float* __restrict__ out,
                int N, int nbins, int npart)
{
    __shared__ float sh_G[NBINS_MAX];
    __shared__ float sh_r[NBINS_MAX];
    __shared__ float sh_red[4];
    const int t  = threadIdx.x;
    const int qi = blockIdx.x;

    const float a00 = cell[0], a01 = cell[1], a02 = cell[2];
    const float a10 = cell[3], a11 = cell[4], a12 = cell[5];
    const float a20 = cell[6], a21 = cell[7], a22 = cell[8];
    const float det = a00*(a11*a22 - a12*a21)
                    - a01*(a10*a22 - a12*a20)
                    + a02*(a10*a21 - a11*a20);
    const float vol     = fabsf(det);
    const float n_pairs = 0.5f * (float)N * (float)(N - 1);
    const float rho     = (float)N / vol;
    const float pref    = vol / n_pairs;

    // Column sums over npart rows -> G(r) in LDS (4 accumulators for MLP).
    for (int k = t; k < nbins; k += blockDim.x) {
        float s0 = 0.0f, s1 = 0.0f, s2 = 0.0f, s3 = 0.0f;
        int p = 0;
        for (; p + 4 <= npart; p += 4) {
            s0 += partial[(size_t)(p+0)*nbins + k];
            s1 += partial[(size_t)(p+1)*nbins + k];
            s2 += partial[(size_t)(p+2)*nbins + k];
            s3 += partial[(size_t)(p+3)*nbins + k];
        }
        for (; p < npart; ++p) s0 += partial[(size_t)p*nbins + k];
        const float summed = (s0 + s1) + (s2 + s3);

        const float r = rbins[k];
        const float g = pref * summed / (FOUR_PI * r * r);
        const float G = COEFF * (g - 1.0f);
        sh_G[k] = G;
        sh_r[k] = r;
        if (qi == 0) out[k] = G;   // G(r)
    }
    __syncthreads();

    // Trapezoid integral for this block's Q.
    const float q    = qbins[qi];
    const float qinv = 1.0f / (q + 1e-10f);
    float acc = 0.0f;
    for (int k = t; k < nbins; k += blockDim.x) {
        const float r    = sh_r[k];
        const float w_lo = (k > 0)         ? (r - sh_r[k - 1]) : 0.0f;
        const float w_hi = (k < nbins - 1) ? (sh_r[k + 1] - r) : 0.0f;
        acc += 0.5f * (w_lo + w_hi) * r * sh_G[k] * __sinf(q * r) * qinv;
    }
#pragma unroll
    for (int off = 32; off > 0; off >>= 1)
        acc += __shfl_down(acc, off, 64);
    if ((t & 63) == 0) sh_red[t >> 6] = acc;
    __syncthreads();
    if (t == 0) {
        const float S = 1.0f + FOUR_PI * rho *
                        (sh_red[0] + sh_red[1] + sh_red[2] + sh_red[3]);
        out[nbins + qi]   = S;               // S(Q)
        out[2*nbins + qi] = q * (S - 1.0f);  // F(Q)
    }
}

// ---------------------------------------------------------------------------
extern "C" void kernel_launch(void* const* d_in, const int* in_sizes, int n_in,
                              void* d_out, int out_size, void* d_ws, size_t ws_size,
                              hipStream_t stream)
{
    const float* pos   = (const float*)d_in[0];  // (N,3) f32
    const float* cell  = (const float*)d_in[1];  // (3,3) f32
    const float* rbins = (const float*)d_in[2];  // (nbins,) f32
    const float* qbins = (const float*)d_in[3];  // (nbins,) f32
    float* out = (float*)d_out;                  // (3, nbins) f32

    const int N     = in_sizes[0] / 3;
    const int nbins = in_sizes[2];
    const int nrp   = (N + 1) / 2;
    const int npart = (nrp < NPART_MAX) ? nrp : NPART_MAX;

    float* partial = (float*)d_ws;               // [npart][nbins]

    hipLaunchKernelGGL(pair_hist_kernel, dim3(npart), dim3(1024), 0, stream,
                       pos, cell, rbins, partial, N, nbins);
    hipLaunchKernelGGL(finalize_kernel, dim3(nbins), dim3(256), 0, stream,
                       partial, cell, rbins, qbins, out, N, nbins, npart);
}

// Round 6
// 90.278 us; speedup vs baseline: 1.7645x; 1.4387x over previous
//
#include <hip/hip_runtime.h>
#include <math.h>

// Problem constants (from reference): w=0.05, b=5.803, single species.
#define NBINS_MAX 512
#define NMAX      1024                 // atom capacity for LDS staging
constexpr float KW       = 0.05f;
constexpr float INV_KW   = 20.0f;      // 1/w
constexpr float GNORM    = 0.3989422804014327f * INV_KW; // 1/(w*sqrt(2pi))
constexpr float COEFF    = 0.33674809f;    // b*b*0.01
constexpr float FOUR_PI  = 12.566370614359172f;

// Fine distance grid for the gather-KDE reformulation.
// R1/R5 showed the LDS KDE scatter (4.85M lane-atomics) runs at ~3 cyc/lane
// regardless of structure -> 52 us. Quantizing d to delta=5e-5 A (u-jitter
// 1e-3 sigma, G-error ~1e-4 << 2e-2) turns the KDE into: one int atomic per
// pair (scatter) + a register-accumulated convolution (gather, no atomics).
constexpr float DELTA     = 5.0e-5f;
constexpr float INV_DELTA = 20000.0f;
#define NFINE (640*1024)               // covers d in [0, 32.7) A; max MIC d ~21.7
constexpr float GWIN      = 9.0f * KW; // gather window +-9 sigma (tail e^-40)

// ---------------------------------------------------------------------------
// Kernel 1: pair scatter. Block rp handles rows (rp, N-1-rp): exactly N-1
// pairs -> perfect balance. One global int atomicAdd per in-window pair,
// scattered over ~200k addresses (no contention chains).
// ---------------------------------------------------------------------------
__global__ void __launch_bounds__(256)
pair_scatter_kernel(const float* __restrict__ pos,
                    const float* __restrict__ cell,
                    const float* __restrict__ rbins,
                    int* __restrict__ fine,     // [NFINE] counts (pre-zeroed)
                    int N, int nbins)
{
    __shared__ float sh_px[NMAX], sh_py[NMAX], sh_pz[NMAX];
    const int t = threadIdx.x;
    for (int i = t; i < N; i += blockDim.x) {
        sh_px[i] = pos[3*i + 0];
        sh_py[i] = pos[3*i + 1];
        sh_pz[i] = pos[3*i + 2];
    }

    // cell and its inverse (wave-uniform)
    float cm[9];
#pragma unroll
    for (int k = 0; k < 9; ++k) cm[k] = cell[k];
    const float a00 = cm[0], a01 = cm[1], a02 = cm[2];
    const float a10 = cm[3], a11 = cm[4], a12 = cm[5];
    const float a20 = cm[6], a21 = cm[7], a22 = cm[8];
    const float det = a00*(a11*a22 - a12*a21)
                    - a01*(a10*a22 - a12*a20)
                    + a02*(a10*a21 - a11*a20);
    const float id = 1.0f / det;
    float im[9];
    im[0] = (a11*a22 - a12*a21)*id;
    im[1] = (a02*a21 - a01*a22)*id;
    im[2] = (a01*a12 - a02*a11)*id;
    im[3] = (a12*a20 - a10*a22)*id;
    im[4] = (a00*a22 - a02*a20)*id;
    im[5] = (a02*a10 - a00*a12)*id;
    im[6] = (a10*a21 - a11*a20)*id;
    im[7] = (a01*a20 - a00*a21)*id;
    im[8] = (a00*a11 - a01*a10)*id;

    const float r0   = rbins[0];
    const float rend = rbins[nbins - 1];
    const float minb = r0   - 3.0f * KW;   // window mask: excludes whole pairs
    const float maxb = rend + 3.0f * KW;

    __syncthreads();

    const int A    = blockIdx.x;
    const int B    = N - 1 - A;
    const int cntA = N - 1 - A;
    const int cntB = (B != A) ? A : 0;     // guard odd-N center row
    const int tot  = cntA + cntB;

    for (int p = t; p < tot; p += blockDim.x) {
        int i, j;
        if (p < cntA) { i = A; j = A + 1 + p; }
        else          { i = B; j = B + 1 + (p - cntA); }

        const float dx = sh_px[j] - sh_px[i];
        const float dy = sh_py[j] - sh_py[i];
        const float dz = sh_pz[j] - sh_pz[i];
        float fx = dx*im[0] + dy*im[3] + dz*im[6];
        float fy = dx*im[1] + dy*im[4] + dz*im[7];
        float fz = dx*im[2] + dy*im[5] + dz*im[8];
        fx -= rintf(fx); fy -= rintf(fy); fz -= rintf(fz);   // min image
        const float mx = fx*cm[0] + fy*cm[3] + fz*cm[6];
        const float my = fx*cm[1] + fy*cm[4] + fz*cm[7];
        const float mz = fx*cm[2] + fy*cm[5] + fz*cm[8];
        const float d  = sqrtf(mx*mx + my*my + mz*mz + 1e-10f);

        if (d > minb && d < maxb) {
            int idx = (int)(d * INV_DELTA);
            if (idx < 0) idx = 0;
            if (idx >= NFINE) idx = NFINE - 1;
            atomicAdd(&fine[idx], 1);      // native int atomic, fire-and-forget
        }
    }
}

// ---------------------------------------------------------------------------
// Kernel 2: gather-KDE. Block k = coarse bin k: sum count_f * exp over the
// +-9 sigma fine window (coalesced reads, register accumulation, NO atomics),
// then G(r_k) -> out[k] and ws G-buffer.
// ---------------------------------------------------------------------------
__global__ void __launch_bounds__(256)
ghist_kernel(const int* __restrict__ fine,
             const float* __restrict__ cell,
             const float* __restrict__ rbins,
             float* __restrict__ Gws,
             float* __restrict__ out,
             int N, int nbins)
{
    __shared__ float sh_red[4];
    const int k = blockIdx.x;
    const int t = threadIdx.x;

    const float rk  = rbins[k];
    int flo = (int)((rk - GWIN) * INV_DELTA);
    int fhi = (int)((rk + GWIN) * INV_DELTA);
    if (flo < 0) flo = 0;
    if (fhi > NFINE - 1) fhi = NFINE - 1;

    float acc = 0.0f;
    for (int f = flo + t; f <= fhi; f += 256) {
        const int c = fine[f];
        const float df = ((float)f + 0.5f) * DELTA;   // fine-bin center
        const float u  = (rk - df) * INV_KW;
        acc += (float)c * __expf(-0.5f * u * u);
    }

#pragma unroll
    for (int off = 32; off > 0; off >>= 1)
        acc += __shfl_down(acc, off, 64);
    if ((t & 63) == 0) sh_red[t >> 6] = acc;
    __syncthreads();

    if (t == 0) {
        const float summed = GNORM * (sh_red[0] + sh_red[1] + sh_red[2] + sh_red[3]);
        const float a00 = cell[0], a01 = cell[1], a02 = cell[2];
        const float a10 = cell[3], a11 = cell[4], a12 = cell[5];
        const float a20 = cell[6], a21 = cell[7], a22 = cell[8];
        const float det = a00*(a11*a22 - a12*a21)
                        - a01*(a10*a22 - a12*a20)
                        + a02*(a10*a21 - a11*a20);
        const float vol     = fabsf(det);
        const float n_pairs = 0.5f * (float)N * (float)(N - 1);
        const float pref    = vol / n_pairs;
        const float g = pref * summed / (FOUR_PI * rk * rk);
        const float G = COEFF * (g - 1.0f);
        out[k]  = G;     // G(r)
        Gws[k]  = G;
    }
}

// ---------------------------------------------------------------------------
// Kernel 3: S(Q), F(Q). Block qi: trapezoid integral over G (L2-hot 1.6 KB).
// ---------------------------------------------------------------------------
__global__ void __launch_bounds__(256)
sq_kernel(const float* __restrict__ Gws,
          const float* __restrict__ cell,
          const float* __restrict__ rbins,
          const float* __restrict__ qbins,
          float* __restrict__ out,
          int N, int nbins)
{
    __shared__ float sh_G[NBINS_MAX];
    __shared__ float sh_r[NBINS_MAX];
    __shared__ float sh_red[4];
    const int qi = blockIdx.x;
    const int t  = threadIdx.x;

    for (int k = t; k < nbins; k += blockDim.x) {
        sh_G[k] = Gws[k];
        sh_r[k] = rbins[k];
    }
    __syncthreads();

    const float a00 = cell[0], a01 = cell[1], a02 = cell[2];
    const float a10 = cell[3], a11 = cell[4], a12 = cell[5];
    const float a20 = cell[6], a21 = cell[7], a22 = cell[8];
    const float det = a00*(a11*a22 - a12*a21)
                    - a01*(a10*a22 - a12*a20)
                    + a02*(a10*a21 - a11*a20);
    const float vol = fabsf(det);
    const float rho = (float)N / vol;

    const float q    = qbins[qi];
    const float qinv = 1.0f / (q + 1e-10f);
    float acc = 0.0f;
    for (int k = t; k < nbins; k += blockDim.x) {
        const float r    = sh_r[k];
        const float w_lo = (k > 0)         ? (r - sh_r[k - 1]) : 0.0f;
        const float w_hi = (k < nbins - 1) ? (sh_r[k + 1] - r) : 0.0f;
        acc += 0.5f * (w_lo + w_hi) * r * sh_G[k] * __sinf(q * r) * qinv;
    }
#pragma unroll
    for (int off = 32; off > 0; off >>= 1)
        acc += __shfl_down(acc, off, 64);
    if ((t & 63) == 0) sh_red[t >> 6] = acc;
    __syncthreads();
    if (t == 0) {
        const float S = 1.0f + FOUR_PI * rho *
                        (sh_red[0] + sh_red[1] + sh_red[2] + sh_red[3]);
        out[nbins + qi]   = S;               // S(Q)
        out[2*nbins + qi] = q * (S - 1.0f);  // F(Q)
    }
}

// ---------------------------------------------------------------------------
extern "C" void kernel_launch(void* const* d_in, const int* in_sizes, int n_in,
                              void* d_out, int out_size, void* d_ws, size_t ws_size,
                              hipStream_t stream)
{
    const float* pos   = (const float*)d_in[0];  // (N,3) f32
    const float* cell  = (const float*)d_in[1];  // (3,3) f32
    const float* rbins = (const float*)d_in[2];  // (nbins,) f32
    const float* qbins = (const float*)d_in[3];  // (nbins,) f32
    float* out = (float*)d_out;                  // (3, nbins) f32

    const int N     = in_sizes[0] / 3;
    const int nbins = in_sizes[2];
    const int nrp   = (N + 1) / 2;               // row-pairs (blocks for scatter)

    int*   fine = (int*)d_ws;                    // [NFINE] counts
    float* Gws  = (float*)((char*)d_ws + (size_t)NFINE * sizeof(int));

    hipMemsetAsync(fine, 0, (size_t)NFINE * sizeof(int), stream);
    hipLaunchKernelGGL(pair_scatter_kernel, dim3(nrp), dim3(256), 0, stream,
                       pos, cell, rbins, fine, N, nbins);
    hipLaunchKernelGGL(ghist_kernel, dim3(nbins), dim3(256), 0, stream,
                       fine, cell, rbins, Gws, out, N, nbins);
    hipLaunchKernelGGL(sq_kernel, dim3(nbins), dim3(256), 0, stream,
                       Gws, cell, rbins, qbins, out, N, nbins);
}